// Round 5
// baseline (666.289 us; speedup 1.0000x reference)
//
#include <hip/hip_runtime.h>
#include <stdint.h>

typedef __bf16   bf16x8  __attribute__((ext_vector_type(8)));
typedef float    f32x4   __attribute__((ext_vector_type(4)));
typedef float    f32x16  __attribute__((ext_vector_type(16)));
typedef uint16_t u16x8   __attribute__((ext_vector_type(8)));

using as1_cvp = const __attribute__((address_space(1))) void*;
using as3_vp  = __attribute__((address_space(3))) void*;

__device__ __forceinline__ uint16_t f2bf(float f) {
    uint32_t u = __float_as_uint(f);
    u += 0x7FFF + ((u >> 16) & 1);          // RNE
    return (uint16_t)(u >> 16);
}

__device__ __forceinline__ void gload16(const void* g, void* l) {
    __builtin_amdgcn_global_load_lds((as1_cvp)g, (as3_vp)l, 16, 0, 0);
}

#define MFMA16(a, b, c) __builtin_amdgcn_mfma_f32_16x16x32_bf16((a), (b), (c), 0, 0, 0)
#define MFMA32(a, b, c) __builtin_amdgcn_mfma_f32_32x32x16_bf16((a), (b), (c), 0, 0, 0)

// ---------------------------------------------------------------- f32 -> bf16
__global__ __launch_bounds__(256)
void cvt_bf16(const float* __restrict__ in, uint16_t* __restrict__ out, int n8)
{
    int i = blockIdx.x * 256 + threadIdx.x;
    if (i >= n8) return;
    const float4* p = reinterpret_cast<const float4*>(in) + (size_t)i * 2;
    float4 a = p[0], b = p[1];
    u16x8 o;
    o[0] = f2bf(a.x); o[1] = f2bf(a.y); o[2] = f2bf(a.z); o[3] = f2bf(a.w);
    o[4] = f2bf(b.x); o[5] = f2bf(b.y); o[6] = f2bf(b.z); o[7] = f2bf(b.w);
    reinterpret_cast<u16x8*>(out)[i] = o;
}

// ---------------------------------------------------------------------------
// 256x256 GEMM, 2 barriers/tile: C = A * Bt^T + bias. A [M x K], Bt [N x K]
// bf16 row-major. 8 waves (2M x 4N), BK=64 as 2 K-halves of 32 (64B LDS
// rows, 16B block ^= (row>>1)&3 swizzle -> conflict-free, measured 0 in r4).
// MFMA 32x32x16 (2495 TF ceiling vs 2176 for 16x16x32). Per wave: out
// 128x64 = acc[4][2] f32x16; per kh-phase 16 MFMA, 8 A-frag + 4 B-frag
// ds_read_b128.
// Tile t: {stage nxt-kh1(t+1); read kh0} B1 {MFMA kh0 || read kh1 ||
// stage cur-kh0(t+2) || MFMA kh1} vmcnt(4) B2.
// B1 protects: all waves' kh0 reads done before cur-kh0 overwritten.
// B2(t-1)+vmcnt(4) guarantees kh0(t),kh1(t) landed (issue order: ...,
// t-1r1: kh1(t), t-1r2: kh0(t+1), vmcnt(4) -> all but last batch landed).
// ---------------------------------------------------------------------------
template <int OUT_BF16>
__global__ __launch_bounds__(512, 2)
void gemm256(const uint16_t* __restrict__ A, const uint16_t* __restrict__ Bt,
             const float* __restrict__ bias, void* __restrict__ Cout,
             int M, int N, int K)
{
    __shared__ uint16_t lds[65536];        // [buf][kh] x (A 256x32 | B 256x32)
    const int NT = K >> 6;                 // K-tiles of 64

    int bid = blockIdx.x;
    bid = (bid & 7) * 32 + (bid >> 3);     // XCD-aware swizzle (nwg=256, %8==0)
    const int bx = bid & 15, by = bid >> 4;
    const int rb = by * 256, cb = bx * 256;

    const int tid  = threadIdx.x;
    const int w    = tid >> 6;
    const int lane = tid & 63;
    const int l32  = lane & 31;            // MFMA row/col within 32-tile
    const int l5   = lane >> 5;            // k-half-of-16 selector
    const int wm   = w >> 2;               // 0..1
    const int wn   = w & 3;                // 0..3
    const int srow = lane >> 2;            // stage: 4 lanes per 64B row
    const int sblk = lane & 3;             // stage: 16B block within row

    f32x16 acc[4][2] = {};

    // stage one 16KB unit (256 rows x 32 k) of A or B, k-half kh, into buf.
    auto stageA = [&](int buf, int kh, int kbase) {
#pragma unroll
        for (int i = 0; i < 2; ++i) {
            const int row = i * 128 + w * 16 + srow;
            const uint16_t* src = A + (size_t)(rb + row) * K + kbase
                                    + ((sblk ^ ((row >> 1) & 3)) << 3);
            gload16(src, &lds[(buf * 2 + kh) * 16384 + i * 4096 + w * 512]);
        }
    };
    auto stageB = [&](int buf, int kh, int kbase) {
#pragma unroll
        for (int i = 0; i < 2; ++i) {
            const int row = i * 128 + w * 16 + srow;
            const uint16_t* src = Bt + (size_t)(cb + row) * K + kbase
                                     + ((sblk ^ ((row >> 1) & 3)) << 3);
            gload16(src, &lds[(buf * 2 + kh) * 16384 + 8192 + i * 4096 + w * 512]);
        }
    };

    // fragment reads for one kh unit: af[4][2], bf[2][2]
    // A-frag (32x32x16): lane holds A[r = base+l32][k = ks*16 + 8*l5 + j]
    auto readA = [&](int base, int mi, int ks) -> bf16x8 {
        const int r = wm * 128 + mi * 32 + l32;
        return *reinterpret_cast<const bf16x8*>(
            &lds[base + r * 32 + (((ks * 2 + l5) ^ ((r >> 1) & 3)) << 3)]);
    };
    auto readB = [&](int base, int ni, int ks) -> bf16x8 {
        const int c = wn * 64 + ni * 32 + l32;
        return *reinterpret_cast<const bf16x8*>(
            &lds[base + 8192 + c * 32 + (((ks * 2 + l5) ^ ((c >> 1) & 3)) << 3)]);
    };

    // ---- prologue: t0 kh0, t0 kh1, t1 kh0 (12 loads; vmcnt(4) -> t0 landed)
    stageA(0, 0, 0);  stageB(0, 0, 0);
    stageA(0, 1, 32); stageB(0, 1, 32);
    stageA(1, 0, 64); stageB(1, 0, 64);
    asm volatile("s_waitcnt vmcnt(4)" ::: "memory");
    __builtin_amdgcn_s_barrier();

    for (int t = 0; t < NT; ++t) {
        const int cur = t & 1, nxt = cur ^ 1;
        const int base0 = (cur * 2 + 0) * 16384;
        const int base1 = (cur * 2 + 1) * 16384;

        // ---- region 1: stage nxt-kh1(t+1), read kh0 fragments
        if (t + 1 < NT) { stageA(nxt, 1, (t + 1) * 64 + 32);
                          stageB(nxt, 1, (t + 1) * 64 + 32); }
        bf16x8 a0[4][2], b0[2][2];
#pragma unroll
        for (int mi = 0; mi < 4; ++mi)
#pragma unroll
            for (int ks = 0; ks < 2; ++ks) a0[mi][ks] = readA(base0, mi, ks);
#pragma unroll
        for (int ni = 0; ni < 2; ++ni)
#pragma unroll
            for (int ks = 0; ks < 2; ++ks) b0[ni][ks] = readB(base0, ni, ks);

        __builtin_amdgcn_sched_barrier(0);
        __builtin_amdgcn_s_barrier();      // B1: kh0 reads done everywhere

        // ---- region 2 (free-running): stage cur-kh0(t+2), read kh1,
        //      MFMA kh0 and kh1 — compiler interleaves, waves overlap.
        if (t + 2 < NT) { stageA(cur, 0, (t + 2) * 64);
                          stageB(cur, 0, (t + 2) * 64); }
        bf16x8 a1[4][2], b1[2][2];
#pragma unroll
        for (int mi = 0; mi < 4; ++mi)
#pragma unroll
            for (int ks = 0; ks < 2; ++ks) a1[mi][ks] = readA(base1, mi, ks);
#pragma unroll
        for (int ni = 0; ni < 2; ++ni)
#pragma unroll
            for (int ks = 0; ks < 2; ++ks) b1[ni][ks] = readB(base1, ni, ks);

        __builtin_amdgcn_s_setprio(1);
#pragma unroll
        for (int ks = 0; ks < 2; ++ks)
#pragma unroll
            for (int mi = 0; mi < 4; ++mi)
#pragma unroll
                for (int ni = 0; ni < 2; ++ni)
                    acc[mi][ni] = MFMA32(a0[mi][ks], b0[ni][ks], acc[mi][ni]);
#pragma unroll
        for (int ks = 0; ks < 2; ++ks)
#pragma unroll
            for (int mi = 0; mi < 4; ++mi)
#pragma unroll
                for (int ni = 0; ni < 2; ++ni)
                    acc[mi][ni] = MFMA32(a1[mi][ks], b1[ni][ks], acc[mi][ni]);
        __builtin_amdgcn_s_setprio(0);

        __builtin_amdgcn_sched_barrier(0);
        if (t >= NT - 2) asm volatile("s_waitcnt vmcnt(0)" ::: "memory");
        else             asm volatile("s_waitcnt vmcnt(4)" ::: "memory");
        __builtin_amdgcn_s_barrier();      // B2: tile boundary
    }

    // ---- epilogue: C/D 32x32 layout col=lane&31, row=(reg&3)+8*(reg>>2)+4*l5
    float bv[2];
#pragma unroll
    for (int ni = 0; ni < 2; ++ni) bv[ni] = bias[cb + wn * 64 + ni * 32 + l32];

#pragma unroll
    for (int mi = 0; mi < 4; ++mi) {
#pragma unroll
        for (int ni = 0; ni < 2; ++ni) {
            const int col = cb + wn * 64 + ni * 32 + l32;
#pragma unroll
            for (int reg = 0; reg < 16; ++reg) {
                const int row = rb + wm * 128 + mi * 32
                              + (reg & 3) + 8 * (reg >> 2) + 4 * l5;
                float v = acc[mi][ni][reg] + bv[ni];
                if (OUT_BF16)
                    ((uint16_t*)Cout)[(size_t)row * N + col] = f2bf(v);
                else
                    ((float*)Cout)[(size_t)row * N + col] = v;
            }
        }
    }
}

// ------------------------------------------------------------------ attention
// One block per (bb, hh). 4 waves; wave w owns query rows [16w, 16w+16).
// Unscaled softmax(Q K^T) V, output scattered through the reference's
// cat/transpose/view permutation directly into Y (bf16 [4096 x 4096]).
__global__ __launch_bounds__(256)
void attn_kernel(const uint16_t* __restrict__ Q, const uint16_t* __restrict__ Kg,
                 const uint16_t* __restrict__ V, uint16_t* __restrict__ Y)
{
    const int bid = blockIdx.x;
    const int hh  = bid & 63;
    const int bb  = bid >> 6;
    const int tid = threadIdx.x;
    const int w   = tid >> 6, lane = tid & 63, g = lane >> 4, l16 = lane & 15;

    __shared__ uint16_t Vt[64 * 64];   // V transposed, XOR-swizzled (8 KB)
    __shared__ uint16_t Pl[64 * 64];   // P bf16, XOR-swizzled (8 KB)

    // ---- stage V transposed: Vt[l][k] = V[k][l], swizzle elem k ^= (l&7)<<3
    {
        const int k  = tid >> 2;
        const int l0 = (tid & 3) * 16;
        const uint16_t* src = V + (size_t)(bb * 64 + k) * 4096 + hh * 64 + l0;
        u16x8 v0 = *reinterpret_cast<const u16x8*>(src);
        u16x8 v1 = *reinterpret_cast<const u16x8*>(src + 8);
#pragma unroll
        for (int i = 0; i < 8; ++i) {
            int l = l0 + i;
            Vt[l * 64 + (k ^ ((l & 7) << 3))] = v0[i];
        }
#pragma unroll
        for (int i = 0; i < 8; ++i) {
            int l = l0 + 8 + i;
            Vt[l * 64 + (k ^ ((l & 7) << 3))] = v1[i];
        }
    }

    // ---- S = Q K^T (rows 16w..16w+16, all 64 cols), direct-global fragments
    f32x4 sa[4] = {};
    {
        const uint16_t* qrow = Q + (size_t)(bb * 64 + w * 16 + l16) * 4096 + hh * 64 + g * 8;
        bf16x8 a0 = *reinterpret_cast<const bf16x8*>(qrow);
        bf16x8 a1 = *reinterpret_cast<const bf16x8*>(qrow + 32);
#pragma unroll
        for (int n = 0; n < 4; ++n) {
            const uint16_t* krow = Kg + (size_t)(bb * 64 + n * 16 + l16) * 4096 + hh * 64 + g * 8;
            bf16x8 b0 = *reinterpret_cast<const bf16x8*>(krow);
            bf16x8 b1 = *reinterpret_cast<const bf16x8*>(krow + 32);
            sa[n] = MFMA16(a0, b0, sa[n]);
            sa[n] = MFMA16(a1, b1, sa[n]);
        }
    }

    // ---- softmax (no 1/sqrt(hd) scale, faithful). Row q = 16w + 4g + j;
    // its 64 values live as regs n=0..3 across the 16-lane group (l16).
    float p[4][4];
#pragma unroll
    for (int j = 0; j < 4; ++j) {
        float mx = fmaxf(fmaxf(sa[0][j], sa[1][j]), fmaxf(sa[2][j], sa[3][j]));
        mx = fmaxf(mx, __shfl_xor(mx, 1));
        mx = fmaxf(mx, __shfl_xor(mx, 2));
        mx = fmaxf(mx, __shfl_xor(mx, 4));
        mx = fmaxf(mx, __shfl_xor(mx, 8));
        float s = 0.f;
#pragma unroll
        for (int n = 0; n < 4; ++n) { p[n][j] = __expf(sa[n][j] - mx); s += p[n][j]; }
        s += __shfl_xor(s, 1);
        s += __shfl_xor(s, 2);
        s += __shfl_xor(s, 4);
        s += __shfl_xor(s, 8);
        float inv = 1.0f / s;
#pragma unroll
        for (int n = 0; n < 4; ++n) p[n][j] *= inv;
    }

    // ---- P -> LDS in A-operand-friendly layout (swizzled)
#pragma unroll
    for (int j = 0; j < 4; ++j) {
        const int q = w * 16 + g * 4 + j;
#pragma unroll
        for (int n = 0; n < 4; ++n) {
            const int kcol = n * 16 + l16;
            Pl[q * 64 + (kcol ^ ((q & 7) << 3))] = f2bf(p[n][j]);
        }
    }
    __syncthreads();   // Vt (all threads) + Pl ready

    // ---- O = P V
    f32x4 oa[4] = {};
    {
        const int qr = w * 16 + l16;
        bf16x8 a0 = *reinterpret_cast<const bf16x8*>(&Pl[qr * 64 + ((g * 8)      ^ ((qr & 7) << 3))]);
        bf16x8 a1 = *reinterpret_cast<const bf16x8*>(&Pl[qr * 64 + ((32 + g * 8) ^ ((qr & 7) << 3))]);
#pragma unroll
        for (int n = 0; n < 4; ++n) {
            const int vr = n * 16 + l16;
            bf16x8 b0 = *reinterpret_cast<const bf16x8*>(&Vt[vr * 64 + ((g * 8)      ^ ((vr & 7) << 3))]);
            bf16x8 b1 = *reinterpret_cast<const bf16x8*>(&Vt[vr * 64 + ((32 + g * 8) ^ ((vr & 7) << 3))]);
            oa[n] = MFMA16(a0, b0, oa[n]);
            oa[n] = MFMA16(a1, b1, oa[n]);
        }
    }

    // ---- permuted store: Ostd[bb,hh,qq,ll] -> Y[b, s, h*64 + l]
#pragma unroll
    for (int n = 0; n < 4; ++n) {
        const int ll = n * 16 + l16;
#pragma unroll
        for (int r = 0; r < 4; ++r) {
            const int qq = w * 16 + g * 4 + r;
            const int b_ = (bb >> 1) + ((ll >= 32) ? 32 : 0);
            const int s_ = ((bb & 1) << 5) + (qq >> 1);
            const int h_ = ((qq & 1) << 5) + (hh >> 1);
            const int l_ = ((hh & 1) << 5) + (ll & 31);
            Y[(size_t)(b_ * 64 + s_) * 4096 + h_ * 64 + l_] = f2bf(oa[n][r]);
        }
    }
}

// ----------------------------------------------------------------------------
extern "C" void kernel_launch(void* const* d_in, const int* in_sizes, int n_in,
                              void* d_out, int out_size, void* d_ws, size_t ws_size,
                              hipStream_t stream)
{
    (void)in_sizes; (void)n_in; (void)out_size; (void)ws_size;

    const float* x  = (const float*)d_in[0];
    const float* Wq = (const float*)d_in[1];
    const float* bq = (const float*)d_in[2];
    const float* Wk = (const float*)d_in[3];
    const float* bk = (const float*)d_in[4];
    const float* Wv = (const float*)d_in[5];
    const float* bv = (const float*)d_in[6];
    const float* Wp = (const float*)d_in[7];
    const float* bp = (const float*)d_in[8];
    float* out = (float*)d_out;

    const size_t NN = 16777216;            // 4096*4096 elements
    uint16_t* xb   = (uint16_t*)d_ws;      // 32 MB, later reused as Y
    uint16_t* wb   = xb + NN;              // 32 MB (sequential weight buffer)
    uint16_t* Qb   = wb + NN;              // 32 MB
    uint16_t* Kb   = Qb + NN;              // 32 MB
    uint16_t* Vb   = Kb + NN;              // 32 MB   (total 160 MB)
    uint16_t* Yb   = xb;

    const int n8 = (int)(NN / 8);
    dim3 cgrid((n8 + 255) / 256), cblk(256);
    dim3 ggrid(256), gblk(512);

    cvt_bf16<<<cgrid, cblk, 0, stream>>>(x, xb, n8);

    cvt_bf16<<<cgrid, cblk, 0, stream>>>(Wq, wb, n8);
    gemm256<1><<<ggrid, gblk, 0, stream>>>(xb, wb, bq, (void*)Qb, 4096, 4096, 4096);

    cvt_bf16<<<cgrid, cblk, 0, stream>>>(Wk, wb, n8);
    gemm256<1><<<ggrid, gblk, 0, stream>>>(xb, wb, bk, (void*)Kb, 4096, 4096, 4096);

    cvt_bf16<<<cgrid, cblk, 0, stream>>>(Wv, wb, n8);
    gemm256<1><<<ggrid, gblk, 0, stream>>>(xb, wb, bv, (void*)Vb, 4096, 4096, 4096);

    attn_kernel<<<dim3(4096), dim3(256), 0, stream>>>(Qb, Kb, Vb, Yb);

    cvt_bf16<<<cgrid, cblk, 0, stream>>>(Wp, wb, n8);
    gemm256<0><<<ggrid, gblk, 0, stream>>>(Yb, wb, bp, (void*)out, 4096, 4096, 4096);
}

// Round 6
// 598.930 us; speedup vs baseline: 1.1125x; 1.1125x over previous
//
#include <hip/hip_runtime.h>
#include <stdint.h>

typedef __bf16   bf16x8  __attribute__((ext_vector_type(8)));
typedef float    f32x4   __attribute__((ext_vector_type(4)));
typedef uint16_t u16x8   __attribute__((ext_vector_type(8)));

using as1_cvp = const __attribute__((address_space(1))) void*;
using as3_vp  = __attribute__((address_space(3))) void*;

__device__ __forceinline__ uint16_t f2bf(float f) {
    uint32_t u = __float_as_uint(f);
    u += 0x7FFF + ((u >> 16) & 1);          // RNE
    return (uint16_t)(u >> 16);
}

__device__ __forceinline__ void gload16(const void* g, void* l) {
    __builtin_amdgcn_global_load_lds((as1_cvp)g, (as3_vp)l, 16, 0, 0);
}

#define MFMA16(a, b, c) __builtin_amdgcn_mfma_f32_16x16x32_bf16((a), (b), (c), 0, 0, 0)

// ---------------------------------------------------------------- f32 -> bf16
__global__ __launch_bounds__(256)
void cvt_bf16(const float* __restrict__ in, uint16_t* __restrict__ out, int n8)
{
    int i = blockIdx.x * 256 + threadIdx.x;
    if (i >= n8) return;
    const float4* p = reinterpret_cast<const float4*>(in) + (size_t)i * 2;
    float4 a = p[0], b = p[1];
    u16x8 o;
    o[0] = f2bf(a.x); o[1] = f2bf(a.y); o[2] = f2bf(a.z); o[3] = f2bf(a.w);
    o[4] = f2bf(b.x); o[5] = f2bf(b.y); o[6] = f2bf(b.z); o[7] = f2bf(b.w);
    reinterpret_cast<u16x8*>(out)[i] = o;
}

// ---------------------------------------------------------------------------
// 256x256 GEMM, pipelined fragments, 4 barriers/tile. C = A*Bt^T + bias.
// A [M x K], Bt [N x K] bf16 row-major. 8 waves (2M x 4N), BK=64 as two
// K-halves of 32 (64B LDS rows, 16B block ^= (row>>1)&3 -> 0 conflicts, r4).
// Per phase: {stage-issue; ds_reads for NEXT phase's frags; MFMA on frags
// read LAST phase}; raw s_barrier at phase end does NOT drain lgkm -> the
// compiler's counted lgkmcnt lets next-phase reads fly under current MFMA.
// ph0 frags (kh0, cross-tile) are read in-phase (only vmcnt-guaranteed at
// the tile boundary). vmcnt(4) once per tile as in r4.
// ---------------------------------------------------------------------------
template <int OUT_BF16>
__global__ __launch_bounds__(512, 2)
void gemm256(const uint16_t* __restrict__ A, const uint16_t* __restrict__ Bt,
             const float* __restrict__ bias, void* __restrict__ Cout,
             int M, int N, int K)
{
    __shared__ uint16_t lds[65536];        // [buf][kh] x (A 256x32 | B 256x32)
    const int NT = K >> 6;                 // K-tiles of 64

    int bid = blockIdx.x;
    bid = (bid & 7) * 32 + (bid >> 3);     // XCD-aware swizzle (nwg=256, %8==0)
    const int bx = bid & 15, by = bid >> 4;
    const int rb = by * 256, cb = bx * 256;

    const int tid  = threadIdx.x;
    const int w    = tid >> 6;
    const int lane = tid & 63;
    const int g    = lane >> 4;
    const int l16  = lane & 15;
    const int wm   = w >> 2;               // 0..1
    const int wn   = w & 3;                // 0..3
    const int srow = lane >> 2;            // stage: 4 lanes per 64B row
    const int sblk = lane & 3;             // stage: 16B block within row

    f32x4 acc[8][4] = {};

    auto stageA = [&](int buf, int kh, int kbase) {
#pragma unroll
        for (int i = 0; i < 2; ++i) {
            const int row = i * 128 + w * 16 + srow;
            const uint16_t* src = A + (size_t)(rb + row) * K + kbase
                                    + ((sblk ^ ((row >> 1) & 3)) << 3);
            gload16(src, &lds[(buf * 2 + kh) * 16384 + i * 4096 + w * 512]);
        }
    };
    auto stageB = [&](int buf, int kh, int kbase) {
#pragma unroll
        for (int i = 0; i < 2; ++i) {
            const int row = i * 128 + w * 16 + srow;
            const uint16_t* src = Bt + (size_t)(cb + row) * K + kbase
                                     + ((sblk ^ ((row >> 1) & 3)) << 3);
            gload16(src, &lds[(buf * 2 + kh) * 16384 + 8192 + i * 4096 + w * 512]);
        }
    };

    // fragment reads (identical addresses to r4: measured 0 bank conflicts)
    auto readA = [&](int base, int grp, bf16x8* dst) {
#pragma unroll
        for (int mi = 0; mi < 4; ++mi) {
            const int r = wm * 128 + grp * 64 + mi * 16 + l16;
            dst[mi] = *reinterpret_cast<const bf16x8*>(
                &lds[base + r * 32 + ((g ^ ((r >> 1) & 3)) << 3)]);
        }
    };
    auto readB = [&](int base, bf16x8* dst) {
#pragma unroll
        for (int n = 0; n < 4; ++n) {
            const int c = wn * 64 + n * 16 + l16;
            dst[n] = *reinterpret_cast<const bf16x8*>(
                &lds[base + 8192 + c * 32 + ((g ^ ((c >> 1) & 3)) << 3)]);
        }
    };

    auto mfma_grp = [&](int grp, const bf16x8* af, const bf16x8* bf) {
        __builtin_amdgcn_s_setprio(1);
#pragma unroll
        for (int mi = 0; mi < 4; ++mi)
#pragma unroll
            for (int n = 0; n < 4; ++n)
                acc[grp * 4 + mi][n] = MFMA16(af[mi], bf[n], acc[grp * 4 + mi][n]);
        __builtin_amdgcn_s_setprio(0);
    };

    // ---- prologue: t0 kh0, t0 kh1, t1 kh0 (12 loads; vmcnt(4) -> t0 landed)
    stageA(0, 0, 0);  stageB(0, 0, 0);
    stageA(0, 1, 32); stageB(0, 1, 32);
    stageA(1, 0, 64); stageB(1, 0, 64);
    asm volatile("s_waitcnt vmcnt(4)" ::: "memory");
    __builtin_amdgcn_s_barrier();

    for (int t = 0; t < NT; ++t) {
        const int cur = t & 1, nxt = cur ^ 1;
        const int b0 = (cur * 2 + 0) * 16384;
        const int b1 = (cur * 2 + 1) * 16384;
        bf16x8 af0[4], af1[4], af2[4], af3[4], bf0[4], bf1[4];

        // ---- ph0: MFMA kh0-grp0 (in-phase reads); prefetch af1(kh0-grp1)
        if (t + 1 < NT) stageA(nxt, 1, (t + 1) * 64 + 32);
        readA(b0, 0, af0); readB(b0, bf0);
        readA(b0, 1, af1);                 // counted-lgkm: flies under MFMA
        mfma_grp(0, af0, bf0);
        __builtin_amdgcn_sched_barrier(0);
        __builtin_amdgcn_s_barrier();

        // ---- ph1: MFMA kh0-grp1; prefetch bf1,af2 (kh1)
        if (t + 1 < NT) stageB(nxt, 1, (t + 1) * 64 + 32);
        readB(b1, bf1);
        readA(b1, 0, af2);
        mfma_grp(1, af1, bf0);
        __builtin_amdgcn_sched_barrier(0);
        __builtin_amdgcn_s_barrier();

        // ---- ph2: MFMA kh1-grp0; prefetch af3 (kh1-grp1)
        if (t + 2 < NT) stageA(cur, 0, (t + 2) * 64);
        readA(b1, 1, af3);
        mfma_grp(0, af2, bf1);
        __builtin_amdgcn_sched_barrier(0);
        __builtin_amdgcn_s_barrier();

        // ---- ph3: MFMA kh1-grp1; tile-boundary vmcnt
        if (t + 2 < NT) stageB(cur, 0, (t + 2) * 64);
        mfma_grp(1, af3, bf1);
        __builtin_amdgcn_sched_barrier(0);
        if (t >= NT - 2) asm volatile("s_waitcnt vmcnt(0)" ::: "memory");
        else             asm volatile("s_waitcnt vmcnt(4)" ::: "memory");
        __builtin_amdgcn_s_barrier();
    }

    // ---- epilogue (16x16 C/D layout: col = l16, row = 4g + r)
    float bv[4];
#pragma unroll
    for (int n = 0; n < 4; ++n) bv[n] = bias[cb + wn * 64 + n * 16 + l16];

#pragma unroll
    for (int m = 0; m < 8; ++m) {
#pragma unroll
        for (int n = 0; n < 4; ++n) {
            const int col = cb + wn * 64 + n * 16 + l16;
#pragma unroll
            for (int r = 0; r < 4; ++r) {
                const int row = rb + wm * 128 + m * 16 + g * 4 + r;
                float v = acc[m][n][r] + bv[n];
                if (OUT_BF16)
                    ((uint16_t*)Cout)[(size_t)row * N + col] = f2bf(v);
                else
                    ((float*)Cout)[(size_t)row * N + col] = v;
            }
        }
    }
}

// ------------------------------------------------------------------ attention
// One block per (bb, hh). 4 waves; wave w owns query rows [16w, 16w+16).
// Unscaled softmax(Q K^T) V, output scattered through the reference's
// cat/transpose/view permutation directly into Y (bf16 [4096 x 4096]).
__global__ __launch_bounds__(256)
void attn_kernel(const uint16_t* __restrict__ Q, const uint16_t* __restrict__ Kg,
                 const uint16_t* __restrict__ V, uint16_t* __restrict__ Y)
{
    const int bid = blockIdx.x;
    const int hh  = bid & 63;
    const int bb  = bid >> 6;
    const int tid = threadIdx.x;
    const int w   = tid >> 6, lane = tid & 63, g = lane >> 4, l16 = lane & 15;

    __shared__ uint16_t Vt[64 * 64];   // V transposed, XOR-swizzled (8 KB)
    __shared__ uint16_t Pl[64 * 64];   // P bf16, XOR-swizzled (8 KB)

    // ---- stage V transposed: Vt[l][k] = V[k][l], swizzle elem k ^= (l&7)<<3
    {
        const int k  = tid >> 2;
        const int l0 = (tid & 3) * 16;
        const uint16_t* src = V + (size_t)(bb * 64 + k) * 4096 + hh * 64 + l0;
        u16x8 v0 = *reinterpret_cast<const u16x8*>(src);
        u16x8 v1 = *reinterpret_cast<const u16x8*>(src + 8);
#pragma unroll
        for (int i = 0; i < 8; ++i) {
            int l = l0 + i;
            Vt[l * 64 + (k ^ ((l & 7) << 3))] = v0[i];
        }
#pragma unroll
        for (int i = 0; i < 8; ++i) {
            int l = l0 + 8 + i;
            Vt[l * 64 + (k ^ ((l & 7) << 3))] = v1[i];
        }
    }

    // ---- S = Q K^T (rows 16w..16w+16, all 64 cols), direct-global fragments
    f32x4 sa[4] = {};
    {
        const uint16_t* qrow = Q + (size_t)(bb * 64 + w * 16 + l16) * 4096 + hh * 64 + g * 8;
        bf16x8 a0 = *reinterpret_cast<const bf16x8*>(qrow);
        bf16x8 a1 = *reinterpret_cast<const bf16x8*>(qrow + 32);
#pragma unroll
        for (int n = 0; n < 4; ++n) {
            const uint16_t* krow = Kg + (size_t)(bb * 64 + n * 16 + l16) * 4096 + hh * 64 + g * 8;
            bf16x8 b0 = *reinterpret_cast<const bf16x8*>(krow);
            bf16x8 b1 = *reinterpret_cast<const bf16x8*>(krow + 32);
            sa[n] = MFMA16(a0, b0, sa[n]);
            sa[n] = MFMA16(a1, b1, sa[n]);
        }
    }

    // ---- softmax (no 1/sqrt(hd) scale, faithful). Row q = 16w + 4g + j;
    // its 64 values live as regs n=0..3 across the 16-lane group (l16).
    float p[4][4];
#pragma unroll
    for (int j = 0; j < 4; ++j) {
        float mx = fmaxf(fmaxf(sa[0][j], sa[1][j]), fmaxf(sa[2][j], sa[3][j]));
        mx = fmaxf(mx, __shfl_xor(mx, 1));
        mx = fmaxf(mx, __shfl_xor(mx, 2));
        mx = fmaxf(mx, __shfl_xor(mx, 4));
        mx = fmaxf(mx, __shfl_xor(mx, 8));
        float s = 0.f;
#pragma unroll
        for (int n = 0; n < 4; ++n) { p[n][j] = __expf(sa[n][j] - mx); s += p[n][j]; }
        s += __shfl_xor(s, 1);
        s += __shfl_xor(s, 2);
        s += __shfl_xor(s, 4);
        s += __shfl_xor(s, 8);
        float inv = 1.0f / s;
#pragma unroll
        for (int n = 0; n < 4; ++n) p[n][j] *= inv;
    }

    // ---- P -> LDS in A-operand-friendly layout (swizzled)
#pragma unroll
    for (int j = 0; j < 4; ++j) {
        const int q = w * 16 + g * 4 + j;
#pragma unroll
        for (int n = 0; n < 4; ++n) {
            const int kcol = n * 16 + l16;
            Pl[q * 64 + (kcol ^ ((q & 7) << 3))] = f2bf(p[n][j]);
        }
    }
    __syncthreads();   // Vt (all threads) + Pl ready

    // ---- O = P V
    f32x4 oa[4] = {};
    {
        const int qr = w * 16 + l16;
        bf16x8 a0 = *reinterpret_cast<const bf16x8*>(&Pl[qr * 64 + ((g * 8)      ^ ((qr & 7) << 3))]);
        bf16x8 a1 = *reinterpret_cast<const bf16x8*>(&Pl[qr * 64 + ((32 + g * 8) ^ ((qr & 7) << 3))]);
#pragma unroll
        for (int n = 0; n < 4; ++n) {
            const int vr = n * 16 + l16;
            bf16x8 b0 = *reinterpret_cast<const bf16x8*>(&Vt[vr * 64 + ((g * 8)      ^ ((vr & 7) << 3))]);
            bf16x8 b1 = *reinterpret_cast<const bf16x8*>(&Vt[vr * 64 + ((32 + g * 8) ^ ((vr & 7) << 3))]);
            oa[n] = MFMA16(a0, b0, oa[n]);
            oa[n] = MFMA16(a1, b1, oa[n]);
        }
    }

    // ---- permuted store: Ostd[bb,hh,qq,ll] -> Y[b, s, h*64 + l]
#pragma unroll
    for (int n = 0; n < 4; ++n) {
        const int ll = n * 16 + l16;
#pragma unroll
        for (int r = 0; r < 4; ++r) {
            const int qq = w * 16 + g * 4 + r;
            const int b_ = (bb >> 1) + ((ll >= 32) ? 32 : 0);
            const int s_ = ((bb & 1) << 5) + (qq >> 1);
            const int h_ = ((qq & 1) << 5) + (hh >> 1);
            const int l_ = ((hh & 1) << 5) + (ll & 31);
            Y[(size_t)(b_ * 64 + s_) * 4096 + h_ * 64 + l_] = f2bf(oa[n][r]);
        }
    }
}

// ----------------------------------------------------------------------------
extern "C" void kernel_launch(void* const* d_in, const int* in_sizes, int n_in,
                              void* d_out, int out_size, void* d_ws, size_t ws_size,
                              hipStream_t stream)
{
    (void)in_sizes; (void)n_in; (void)out_size; (void)ws_size;

    const float* x  = (const float*)d_in[0];
    const float* Wq = (const float*)d_in[1];
    const float* bq = (const float*)d_in[2];
    const float* Wk = (const float*)d_in[3];
    const float* bk = (const float*)d_in[4];
    const float* Wv = (const float*)d_in[5];
    const float* bv = (const float*)d_in[6];
    const float* Wp = (const float*)d_in[7];
    const float* bp = (const float*)d_in[8];
    float* out = (float*)d_out;

    const size_t NN = 16777216;            // 4096*4096 elements
    uint16_t* xb   = (uint16_t*)d_ws;      // 32 MB, later reused as Y
    uint16_t* wb   = xb + NN;              // 32 MB (sequential weight buffer)
    uint16_t* Qb   = wb + NN;              // 32 MB
    uint16_t* Kb   = Qb + NN;              // 32 MB
    uint16_t* Vb   = Kb + NN;              // 32 MB   (total 160 MB)
    uint16_t* Yb   = xb;

    const int n8 = (int)(NN / 8);
    dim3 cgrid((n8 + 255) / 256), cblk(256);
    dim3 ggrid(256), gblk(512);

    cvt_bf16<<<cgrid, cblk, 0, stream>>>(x, xb, n8);

    cvt_bf16<<<cgrid, cblk, 0, stream>>>(Wq, wb, n8);
    gemm256<1><<<ggrid, gblk, 0, stream>>>(xb, wb, bq, (void*)Qb, 4096, 4096, 4096);

    cvt_bf16<<<cgrid, cblk, 0, stream>>>(Wk, wb, n8);
    gemm256<1><<<ggrid, gblk, 0, stream>>>(xb, wb, bk, (void*)Kb, 4096, 4096, 4096);

    cvt_bf16<<<cgrid, cblk, 0, stream>>>(Wv, wb, n8);
    gemm256<1><<<ggrid, gblk, 0, stream>>>(xb, wb, bv, (void*)Vb, 4096, 4096, 4096);

    attn_kernel<<<dim3(4096), dim3(256), 0, stream>>>(Qb, Kb, Vb, Yb);

    cvt_bf16<<<cgrid, cblk, 0, stream>>>(Wp, wb, n8);
    gemm256<0><<<ggrid, gblk, 0, stream>>>(Yb, wb, bp, (void*)out, 4096, 4096, 4096);
}